// Round 1
// baseline (320.421 us; speedup 1.0000x reference)
//
#include <hip/hip_runtime.h>
#include <math.h>

#define HIDDEN 64

// Pass 1: deg[v] += ew[e] for each edge (self-loop +1 added later).
__global__ void k_deg(const int* __restrict__ dst, const float* __restrict__ ew,
                      float* __restrict__ deg, int E) {
    int e = blockIdx.x * blockDim.x + threadIdx.x;
    if (e < E) atomicAdd(&deg[dst[e]], ew[e]);
}

// Pass 2: dinv[i] = rsqrt(deg+1); s[i] init with self-loop term dinv^2 * x[i].
// dinv overwrites deg in place.
__global__ void k_node_init(const float* __restrict__ x, float* __restrict__ deg_dinv,
                            float* __restrict__ s, int N) {
    int i = blockIdx.x * blockDim.x + threadIdx.x;
    if (i < N) {
        float d = deg_dinv[i] + 1.0f;            // self-loop weight 1
        float dinv = d > 0.0f ? rsqrtf(d) : 0.0f;
        deg_dinv[i] = dinv;
        s[i] = dinv * dinv * x[i];
    }
}

// Pass 3: s[dst] += dinv[src]*ew*dinv[dst]*x[src]
__global__ void k_edge_agg(const int* __restrict__ src, const int* __restrict__ dst,
                           const float* __restrict__ ew, const float* __restrict__ x,
                           const float* __restrict__ dinv, float* __restrict__ s, int E) {
    int e = blockIdx.x * blockDim.x + threadIdx.x;
    if (e < E) {
        int u = src[e], v = dst[e];
        float val = dinv[u] * ew[e] * dinv[v] * x[u];
        atomicAdd(&s[v], val);
    }
}

// Precompute fused coefficients:
//   vz[j] = sum_k Wz[k]*Lz[k][j]          cz[j] = sum_k bz[k]*Lz[k][j] + lbz[j]
//   vh[j] = sum_k Wh[k]*Lh[k][j]          ch[j] = sum_k bh[k]*Lh[k][j] + lbh[j]
// (Only the top 64 rows of Lz/Lh matter since H0 = 0; R branch is dead.)
__global__ void k_coeff(const float* __restrict__ Wz, const float* __restrict__ bz,
                        const float* __restrict__ Lz, const float* __restrict__ lbz,
                        const float* __restrict__ Wh, const float* __restrict__ bh,
                        const float* __restrict__ Lh, const float* __restrict__ lbh,
                        float* __restrict__ coeff) {
    int j = threadIdx.x;
    if (j < HIDDEN) {
        float vz = 0.f, cz = 0.f, vh = 0.f, ch = 0.f;
        for (int k = 0; k < HIDDEN; ++k) {
            float lz = Lz[k * HIDDEN + j];
            float lh = Lh[k * HIDDEN + j];
            vz += Wz[k] * lz;
            cz += bz[k] * lz;
            vh += Wh[k] * lh;
            ch += bh[k] * lh;
        }
        coeff[j]         = vz;
        coeff[64 + j]    = cz + lbz[j];
        coeff[128 + j]   = vh;
        coeff[192 + j]   = ch + lbh[j];
    }
}

// Final: out[i] = sum_j relu((1-sigmoid(s*vz_j+cz_j)) * tanh(s*vh_j+ch_j)) * Wout[j] + bout
__global__ void k_out(const float* __restrict__ s, const float* __restrict__ coeff,
                      const float* __restrict__ Wout, const float* __restrict__ bout,
                      float* __restrict__ out, int N) {
    __shared__ float c[5 * HIDDEN];
    __shared__ float b0;
    if (threadIdx.x < 4 * HIDDEN) c[threadIdx.x] = coeff[threadIdx.x];
    if (threadIdx.x < HIDDEN) c[4 * HIDDEN + threadIdx.x] = Wout[threadIdx.x];
    if (threadIdx.x == 0) b0 = bout[0];
    __syncthreads();
    int i = blockIdx.x * blockDim.x + threadIdx.x;
    if (i < N) {
        float si = s[i];
        float acc = b0;
        #pragma unroll
        for (int j = 0; j < HIDDEN; ++j) {
            float zp = si * c[j] + c[64 + j];
            float hp = si * c[128 + j] + c[192 + j];
            float z = 1.0f / (1.0f + __expf(-zp));
            float t = tanhf(hp);
            float hn = (1.0f - z) * t;
            hn = hn > 0.0f ? hn : 0.0f;
            acc = fmaf(hn, c[256 + j], acc);
        }
        out[i] = acc;
    }
}

extern "C" void kernel_launch(void* const* d_in, const int* in_sizes, int n_in,
                              void* d_out, int out_size, void* d_ws, size_t ws_size,
                              hipStream_t stream) {
    const float* x    = (const float*)d_in[0];
    const float* ew   = (const float*)d_in[1];
    const float* Wz   = (const float*)d_in[2];
    const float* bz   = (const float*)d_in[3];
    const float* Lz   = (const float*)d_in[4];
    const float* lbz  = (const float*)d_in[5];
    // d_in[6..9] = Wr, br, Lr, lbr — dead code (H0 = 0 makes R unused)
    const float* Wh   = (const float*)d_in[10];
    const float* bh   = (const float*)d_in[11];
    const float* Lh   = (const float*)d_in[12];
    const float* lbh  = (const float*)d_in[13];
    const float* Wout = (const float*)d_in[14];
    const float* bout = (const float*)d_in[15];
    const int*   eidx = (const int*)d_in[16];

    const int N = in_sizes[0];          // x is [N,1]
    const int E = in_sizes[1];          // edge_weight is [E]
    const int* src = eidx;              // edge_index[0]
    const int* dst = eidx + E;          // edge_index[1]

    float* deg   = (float*)d_ws;        // N floats (becomes dinv in place)
    float* s     = deg + N;             // N floats
    float* coeff = s + N;               // 4*64 floats

    const int TB = 256;
    hipMemsetAsync(deg, 0, (size_t)N * sizeof(float), stream);
    k_deg<<<(E + TB - 1) / TB, TB, 0, stream>>>(dst, ew, deg, E);
    k_node_init<<<(N + TB - 1) / TB, TB, 0, stream>>>(x, deg, s, N);
    k_edge_agg<<<(E + TB - 1) / TB, TB, 0, stream>>>(src, dst, ew, x, deg, s, E);
    k_coeff<<<1, HIDDEN, 0, stream>>>(Wz, bz, Lz, lbz, Wh, bh, Lh, lbh, coeff);
    k_out<<<(N + TB - 1) / TB, TB, 0, stream>>>(s, coeff, Wout, bout, (float*)d_out, N);
}

// Round 2
// 308.806 us; speedup vs baseline: 1.0376x; 1.0376x over previous
//
#include <hip/hip_runtime.h>
#include <math.h>

#define HIDDEN 64
#define NXCD 8

// Which XCD is this wave on? HW_REG_XCC_ID = hwreg 20 (gfx940+), 4 bits.
__device__ __forceinline__ int xcc_id() {
    int v = __builtin_amdgcn_s_getreg((3 << 11) | (0 << 6) | 20); // size=4,offset=0,id=20
    return v & (NXCD - 1);
}

// Workgroup-scope relaxed atomic add: executes in the local (XCD) TCC and the
// line stays cached there, instead of being forwarded to the device coherence
// point per-op like default agent-scope atomicAdd. All workgroups on one XCD
// share that TCC, so this is atomic among every writer of a per-XCD replica.
__device__ __forceinline__ void atomic_add_local(float* p, float v) {
    __hip_atomic_fetch_add(p, v, __ATOMIC_RELAXED, __HIP_MEMORY_SCOPE_WORKGROUP);
}

// Pass 1: degbuf[xcc][v] += ew[e]
__global__ void k_deg(const int* __restrict__ dst, const float* __restrict__ ew,
                      float* __restrict__ degbuf, int N, int E) {
    int e = blockIdx.x * blockDim.x + threadIdx.x;
    float* mybuf = degbuf + (size_t)xcc_id() * N;
    if (e < E) atomic_add_local(&mybuf[dst[e]], ew[e]);
}

// Pass 2: reduce 8 deg replicas, dinv = rsqrt(deg+1), w = dinv*x.
// Block 0 additionally computes the fused GRU coefficients (H0=0 ⇒ only the
// top 64 rows of Lz/Lh matter; the R gate is dead code).
__global__ void k_node(const float* __restrict__ x, const float* __restrict__ degbuf,
                       float* __restrict__ dinv, float* __restrict__ w, int N,
                       const float* __restrict__ Wz, const float* __restrict__ bz,
                       const float* __restrict__ Lz, const float* __restrict__ lbz,
                       const float* __restrict__ Wh, const float* __restrict__ bh,
                       const float* __restrict__ Lh, const float* __restrict__ lbh,
                       float* __restrict__ coeff) {
    int i = blockIdx.x * blockDim.x + threadIdx.x;
    if (i < N) {
        float d = 1.0f;  // self-loop weight
        #pragma unroll
        for (int k = 0; k < NXCD; ++k) d += degbuf[(size_t)k * N + i];
        float di = rsqrtf(d);
        dinv[i] = di;
        w[i] = di * x[i];
    }
    if (blockIdx.x == 0 && threadIdx.x < HIDDEN) {
        int j = threadIdx.x;
        float vz = 0.f, cz = 0.f, vh = 0.f, ch = 0.f;
        for (int k = 0; k < HIDDEN; ++k) {
            float lz = Lz[k * HIDDEN + j];
            float lh = Lh[k * HIDDEN + j];
            vz += Wz[k] * lz;
            cz += bz[k] * lz;
            vh += Wh[k] * lh;
            ch += bh[k] * lh;
        }
        coeff[j]       = vz;
        coeff[64 + j]  = cz + lbz[j];
        coeff[128 + j] = vh;
        coeff[192 + j] = ch + lbh[j];
    }
}

// Pass 3: gbuf[xcc][v] += w[src]*ew   (dinv[v] factor deferred to k_out)
__global__ void k_edge(const int* __restrict__ src, const int* __restrict__ dst,
                       const float* __restrict__ ew, const float* __restrict__ w,
                       float* __restrict__ gbuf, int N, int E) {
    int e = blockIdx.x * blockDim.x + threadIdx.x;
    float* mybuf = gbuf + (size_t)xcc_id() * N;
    if (e < E) {
        int u = src[e], v = dst[e];
        atomic_add_local(&mybuf[v], w[u] * ew[e]);
    }
}

// Pass 4: s = dinv*(sum of g replicas) + dinv*w  (= dinv^2*x self-loop term),
// then out[i] = sum_j relu((1-sigmoid(s*vz+cz)) * tanh(s*vh+ch)) * Wout_j + bout
__global__ void k_out(const float* __restrict__ gbuf, const float* __restrict__ dinv,
                      const float* __restrict__ w, const float* __restrict__ coeff,
                      const float* __restrict__ Wout, const float* __restrict__ bout,
                      float* __restrict__ out, int N) {
    __shared__ float c[5 * HIDDEN];
    __shared__ float b0;
    if (threadIdx.x < 4 * HIDDEN) c[threadIdx.x] = coeff[threadIdx.x];
    if (threadIdx.x < HIDDEN) c[4 * HIDDEN + threadIdx.x] = Wout[threadIdx.x];
    if (threadIdx.x == 0) b0 = bout[0];
    __syncthreads();
    int i = blockIdx.x * blockDim.x + threadIdx.x;
    if (i < N) {
        float g = 0.0f;
        #pragma unroll
        for (int k = 0; k < NXCD; ++k) g += gbuf[(size_t)k * N + i];
        float di = dinv[i];
        float si = di * g + di * w[i];
        float acc = b0;
        #pragma unroll
        for (int j = 0; j < HIDDEN; ++j) {
            float zp = si * c[j] + c[64 + j];
            float hp = si * c[128 + j] + c[192 + j];
            float z = 1.0f / (1.0f + __expf(-zp));
            float t = tanhf(hp);
            float hn = (1.0f - z) * t;
            hn = hn > 0.0f ? hn : 0.0f;
            acc = fmaf(hn, c[256 + j], acc);
        }
        out[i] = acc;
    }
}

extern "C" void kernel_launch(void* const* d_in, const int* in_sizes, int n_in,
                              void* d_out, int out_size, void* d_ws, size_t ws_size,
                              hipStream_t stream) {
    const float* x    = (const float*)d_in[0];
    const float* ew   = (const float*)d_in[1];
    const float* Wz   = (const float*)d_in[2];
    const float* bz   = (const float*)d_in[3];
    const float* Lz   = (const float*)d_in[4];
    const float* lbz  = (const float*)d_in[5];
    // d_in[6..9] = Wr, br, Lr, lbr — dead (H0 = 0 makes the R gate unused)
    const float* Wh   = (const float*)d_in[10];
    const float* bh   = (const float*)d_in[11];
    const float* Lh   = (const float*)d_in[12];
    const float* lbh  = (const float*)d_in[13];
    const float* Wout = (const float*)d_in[14];
    const float* bout = (const float*)d_in[15];
    const int*   eidx = (const int*)d_in[16];

    const int N = in_sizes[0];          // x is [N,1]
    const int E = in_sizes[1];          // edge_weight is [E]
    const int* src = eidx;              // edge_index[0]
    const int* dst = eidx + E;          // edge_index[1]

    float* degbuf = (float*)d_ws;               // NXCD * N
    float* gbuf   = degbuf + (size_t)NXCD * N;  // NXCD * N
    float* dinv   = gbuf + (size_t)NXCD * N;    // N
    float* w      = dinv + N;                   // N
    float* coeff  = w + N;                      // 4*HIDDEN

    const int TB = 256;
    // zero both replica sets in one memset (contiguous)
    hipMemsetAsync(degbuf, 0, (size_t)2 * NXCD * N * sizeof(float), stream);
    k_deg<<<(E + TB - 1) / TB, TB, 0, stream>>>(dst, ew, degbuf, N, E);
    k_node<<<(N + TB - 1) / TB, TB, 0, stream>>>(x, degbuf, dinv, w, N,
                                                 Wz, bz, Lz, lbz, Wh, bh, Lh, lbh, coeff);
    k_edge<<<(E + TB - 1) / TB, TB, 0, stream>>>(src, dst, ew, w, gbuf, N, E);
    k_out<<<(N + TB - 1) / TB, TB, 0, stream>>>(gbuf, dinv, w, coeff, Wout, bout,
                                                (float*)d_out, N);
}

// Round 3
// 235.350 us; speedup vs baseline: 1.3615x; 1.3121x over previous
//
#include <hip/hip_runtime.h>
#include <math.h>

#define HIDDEN 64
#define RANGE 16384          // nodes per LDS bin range (64 KB of f32 bins)

// ---------------------------------------------------------------------------
// Binning scatter-add without global atomics.
// Grid = nchunks * nranges blocks, chunk-major (blockIdx = c*nranges + r).
// Each block: zero 16K LDS bins; stream its edge chunk; ds_add_f32 for edges
// whose dst falls in its range; flush bins with plain coalesced stores to a
// private partials[c][base..base+rsize) slice. Every partials slot is written
// by exactly one block, so no pre-zeroing of d_ws is needed.
// ---------------------------------------------------------------------------
template <bool WEIGHTED>
__global__ __launch_bounds__(1024)
void k_bin(const int* __restrict__ dst, const int* __restrict__ src,
           const float* __restrict__ ew, const float* __restrict__ w,
           float* __restrict__ partials, int N, int E, int nchunks, int nranges) {
    __shared__ float bins[RANGE];
    const int r = blockIdx.x % nranges;
    const int c = blockIdx.x / nranges;
    const int base = r * RANGE;
    const int rsize = min(RANGE, N - base);

    for (int i = threadIdx.x; i < rsize; i += blockDim.x) bins[i] = 0.0f;
    __syncthreads();

    const int e0 = (int)((long long)E * c / nchunks);
    const int e1 = (int)((long long)E * (c + 1) / nchunks);
    for (int e = e0 + threadIdx.x; e < e1; e += blockDim.x) {
        int v = dst[e];
        unsigned local = (unsigned)(v - base);
        if (local < (unsigned)rsize) {
            float val;
            if (WEIGHTED) val = w[src[e]] * ew[e];
            else          val = ew[e];
            atomicAdd(&bins[local], val);     // LDS atomic (ds_add_f32)
        }
    }
    __syncthreads();

    float* outp = partials + (size_t)c * N + base;
    for (int i = threadIdx.x; i < rsize; i += blockDim.x) outp[i] = bins[i];
}

// ---------------------------------------------------------------------------
// Reduce deg partials -> dinv = rsqrt(deg+1), w = dinv*x.
// Block 0 also computes fused GRU coefficients (H0=0 => only top 64 rows of
// Lz/Lh matter; the R gate is dead code).
// ---------------------------------------------------------------------------
__global__ void k_node(const float* __restrict__ x, const float* __restrict__ partials,
                       float* __restrict__ dinv, float* __restrict__ w,
                       int N, int nchunks,
                       const float* __restrict__ Wz, const float* __restrict__ bz,
                       const float* __restrict__ Lz, const float* __restrict__ lbz,
                       const float* __restrict__ Wh, const float* __restrict__ bh,
                       const float* __restrict__ Lh, const float* __restrict__ lbh,
                       float* __restrict__ coeff) {
    int i = blockIdx.x * blockDim.x + threadIdx.x;
    if (i < N) {
        float d = 1.0f;   // self-loop
        for (int k = 0; k < nchunks; ++k) d += partials[(size_t)k * N + i];
        float di = rsqrtf(d);
        dinv[i] = di;
        w[i] = di * x[i];
    }
    if (blockIdx.x == 0 && threadIdx.x < HIDDEN) {
        int j = threadIdx.x;
        float vz = 0.f, cz = 0.f, vh = 0.f, ch = 0.f;
        for (int k = 0; k < HIDDEN; ++k) {
            float lz = Lz[k * HIDDEN + j];
            float lh = Lh[k * HIDDEN + j];
            vz += Wz[k] * lz;
            cz += bz[k] * lz;
            vh += Wh[k] * lh;
            ch += bh[k] * lh;
        }
        coeff[j]       = vz;
        coeff[64 + j]  = cz + lbz[j];
        coeff[128 + j] = vh;
        coeff[192 + j] = ch + lbh[j];
    }
}

// ---------------------------------------------------------------------------
// Reduce agg partials, add self-loop, apply fused GRU + output head:
//   s = dinv*(sum_c P[c][i] + w[i])          (dinv*w = dinv^2*x self-loop)
//   out[i] = sum_j relu((1-sigmoid(s*vz+cz)) * tanh(s*vh+ch)) * Wout_j + bout
// ---------------------------------------------------------------------------
__global__ void k_out(const float* __restrict__ partials, const float* __restrict__ dinv,
                      const float* __restrict__ w, const float* __restrict__ coeff,
                      const float* __restrict__ Wout, const float* __restrict__ bout,
                      float* __restrict__ out, int N, int nchunks) {
    __shared__ float c[5 * HIDDEN];
    __shared__ float b0;
    if (threadIdx.x < 4 * HIDDEN) c[threadIdx.x] = coeff[threadIdx.x];
    if (threadIdx.x < HIDDEN) c[4 * HIDDEN + threadIdx.x] = Wout[threadIdx.x];
    if (threadIdx.x == 0) b0 = bout[0];
    __syncthreads();
    int i = blockIdx.x * blockDim.x + threadIdx.x;
    if (i < N) {
        float g = w[i];
        for (int k = 0; k < nchunks; ++k) g += partials[(size_t)k * N + i];
        float si = dinv[i] * g;
        float acc = b0;
        #pragma unroll
        for (int j = 0; j < HIDDEN; ++j) {
            float zp = si * c[j] + c[64 + j];
            float hp = si * c[128 + j] + c[192 + j];
            float z = 1.0f / (1.0f + __expf(-zp));
            float t = tanhf(hp);
            float hn = (1.0f - z) * t;
            hn = hn > 0.0f ? hn : 0.0f;
            acc = fmaf(hn, c[256 + j], acc);
        }
        out[i] = acc;
    }
}

extern "C" void kernel_launch(void* const* d_in, const int* in_sizes, int n_in,
                              void* d_out, int out_size, void* d_ws, size_t ws_size,
                              hipStream_t stream) {
    const float* x    = (const float*)d_in[0];
    const float* ew   = (const float*)d_in[1];
    const float* Wz   = (const float*)d_in[2];
    const float* bz   = (const float*)d_in[3];
    const float* Lz   = (const float*)d_in[4];
    const float* lbz  = (const float*)d_in[5];
    // d_in[6..9] = Wr, br, Lr, lbr — dead (H0 = 0 makes the R gate unused)
    const float* Wh   = (const float*)d_in[10];
    const float* bh   = (const float*)d_in[11];
    const float* Lh   = (const float*)d_in[12];
    const float* lbh  = (const float*)d_in[13];
    const float* Wout = (const float*)d_in[14];
    const float* bout = (const float*)d_in[15];
    const int*   eidx = (const int*)d_in[16];

    const int N = in_sizes[0];          // x is [N,1]
    const int E = in_sizes[1];          // edge_weight is [E]
    const int* src = eidx;              // edge_index[0]
    const int* dst = eidx + E;          // edge_index[1]

    const int nranges = (N + RANGE - 1) / RANGE;   // 7 for N=100000

    // Workspace: partials[nchunks][N] + dinv[N] + w[N] + coeff[256].
    // Adapt nchunks to ws_size (constant across calls -> same work every call).
    size_t fixed = ((size_t)2 * N + 4 * HIDDEN + 64) * sizeof(float);
    int nchunks = 64;
    while (nchunks > 4 && (size_t)nchunks * N * sizeof(float) + fixed > ws_size)
        nchunks >>= 1;

    float* partials = (float*)d_ws;                       // nchunks * N
    float* dinv     = partials + (size_t)nchunks * N;     // N
    float* w        = dinv + N;                           // N
    float* coeff    = w + N;                              // 4*HIDDEN

    const int TB = 256;
    const int grid_bin = nchunks * nranges;

    // Pass A: bin edge weights -> deg partials (no global atomics anywhere)
    k_bin<false><<<grid_bin, 1024, 0, stream>>>(dst, src, ew, (const float*)nullptr,
                                                partials, N, E, nchunks, nranges);
    // deg -> dinv, w = dinv*x; plus GRU coefficient fusion
    k_node<<<(N + TB - 1) / TB, TB, 0, stream>>>(x, partials, dinv, w, N, nchunks,
                                                 Wz, bz, Lz, lbz, Wh, bh, Lh, lbh, coeff);
    // Pass B: bin w[src]*ew -> aggregation partials
    k_bin<true><<<grid_bin, 1024, 0, stream>>>(dst, src, ew, w,
                                               partials, N, E, nchunks, nranges);
    // Reduce + fused GRU + output head
    k_out<<<(N + TB - 1) / TB, TB, 0, stream>>>(partials, dinv, w, coeff, Wout, bout,
                                                (float*)d_out, N, nchunks);
}

// Round 4
// 159.289 us; speedup vs baseline: 2.0116x; 1.4775x over previous
//
#include <hip/hip_runtime.h>
#include <math.h>

#define HIDDEN 64
#define RANGE 16384          // nodes per LDS bin range (64 KB of f32 bins)
#define G_CHUNKS 32          // compile-time edge-chunk count (partials streams)

// ---------------------------------------------------------------------------
// Binning scatter-add without global atomics.
// Grid = G_CHUNKS * nranges blocks (blockIdx = c*nranges + r).
// Each block: zero 16K LDS bins; stream its edge chunk with int4/float4 loads;
// ds_add_f32 for edges whose dst is in its range; flush bins with float4
// stores to a private partials[c][r] slice (each slot written by exactly one
// block -> no pre-zeroing of d_ws needed).
// ---------------------------------------------------------------------------
template <bool WEIGHTED>
__global__ __launch_bounds__(1024)
void k_bin(const int* __restrict__ dst, const int* __restrict__ src,
           const float* __restrict__ ew, const float* __restrict__ w,
           float* __restrict__ partials, int N, int E, int nranges) {
    __shared__ float bins[RANGE];
    const int r = blockIdx.x % nranges;
    const int c = blockIdx.x / nranges;
    const int base = r * RANGE;
    const unsigned rsize = (unsigned)min(RANGE, N - base);

    float4* b4 = (float4*)bins;
    for (int i = threadIdx.x; i < RANGE / 4; i += blockDim.x)
        b4[i] = make_float4(0.f, 0.f, 0.f, 0.f);
    __syncthreads();

    // chunk bounds, starts rounded to multiples of 4 for aligned int4 loads
    long long e0 = (((long long)E * c) / G_CHUNKS) & ~3LL;
    long long e1 = (c == G_CHUNKS - 1) ? (long long)E
                                       : ((((long long)E * (c + 1)) / G_CHUNKS) & ~3LL);
    const int nvec = (int)((e1 - e0) >> 2);
    const int4*   dst4 = (const int4*)(dst + e0);
    const float4* ew4  = (const float4*)(ew + e0);
    const int4*   src4 = (const int4*)(src + e0);

    for (int i = threadIdx.x; i < nvec; i += blockDim.x) {
        int4   d = dst4[i];
        float4 t = ew4[i];
        if (WEIGHTED) {
            int4 s = src4[i];
            unsigned l0 = (unsigned)(d.x - base);
            unsigned l1 = (unsigned)(d.y - base);
            unsigned l2 = (unsigned)(d.z - base);
            unsigned l3 = (unsigned)(d.w - base);
            if (l0 < rsize) atomicAdd(&bins[l0], w[s.x] * t.x);
            if (l1 < rsize) atomicAdd(&bins[l1], w[s.y] * t.y);
            if (l2 < rsize) atomicAdd(&bins[l2], w[s.z] * t.z);
            if (l3 < rsize) atomicAdd(&bins[l3], w[s.w] * t.w);
        } else {
            unsigned l0 = (unsigned)(d.x - base);
            unsigned l1 = (unsigned)(d.y - base);
            unsigned l2 = (unsigned)(d.z - base);
            unsigned l3 = (unsigned)(d.w - base);
            if (l0 < rsize) atomicAdd(&bins[l0], t.x);
            if (l1 < rsize) atomicAdd(&bins[l1], t.y);
            if (l2 < rsize) atomicAdd(&bins[l2], t.z);
            if (l3 < rsize) atomicAdd(&bins[l3], t.w);
        }
    }
    // scalar tail (< 4 edges, last chunk only)
    for (long long e = e0 + ((long long)nvec << 2) + threadIdx.x; e < e1; e += blockDim.x) {
        unsigned l = (unsigned)(dst[e] - base);
        if (l < rsize) {
            float v = WEIGHTED ? w[src[e]] * ew[e] : ew[e];
            atomicAdd(&bins[l], v);
        }
    }
    __syncthreads();

    float4* outp = (float4*)(partials + ((size_t)c * nranges + r) * RANGE);
    for (int i = threadIdx.x; i < RANGE / 4; i += blockDim.x) outp[i] = b4[i];
}

// ---------------------------------------------------------------------------
// Reduce deg partials (32 unrolled streams) -> dinv = rsqrt(deg+1), w = dinv*x.
// Block 0 also computes fused GRU coefficients (H0=0 => only top 64 rows of
// Lz/Lh matter; the R gate is dead code).
// ---------------------------------------------------------------------------
__global__ void k_node(const float* __restrict__ x, const float* __restrict__ partials,
                       float* __restrict__ dinv, float* __restrict__ w,
                       int N, int nranges,
                       const float* __restrict__ Wz, const float* __restrict__ bz,
                       const float* __restrict__ Lz, const float* __restrict__ lbz,
                       const float* __restrict__ Wh, const float* __restrict__ bh,
                       const float* __restrict__ Lh, const float* __restrict__ lbh,
                       float* __restrict__ coeff) {
    int i = blockIdx.x * blockDim.x + threadIdx.x;
    if (i < N) {
        int r = i / RANGE, local = i % RANGE;
        const float* p = partials + (size_t)r * RANGE + local;
        float d = 1.0f;   // self-loop
        #pragma unroll
        for (int c = 0; c < G_CHUNKS; ++c)
            d += p[(size_t)c * nranges * RANGE];
        float di = rsqrtf(d);
        dinv[i] = di;
        w[i] = di * x[i];
    }
    if (blockIdx.x == 0 && threadIdx.x < HIDDEN) {
        int j = threadIdx.x;
        float vz = 0.f, cz = 0.f, vh = 0.f, ch = 0.f;
        for (int k = 0; k < HIDDEN; ++k) {
            float lz = Lz[k * HIDDEN + j];
            float lh = Lh[k * HIDDEN + j];
            vz += Wz[k] * lz;
            cz += bz[k] * lz;
            vh += Wh[k] * lh;
            ch += bh[k] * lh;
        }
        coeff[j]       = vz;
        coeff[64 + j]  = cz + lbz[j];
        coeff[128 + j] = vh;
        coeff[192 + j] = ch + lbh[j];
    }
}

// ---------------------------------------------------------------------------
// Reduce agg partials, add self-loop, fused GRU + output head:
//   s = dinv*(sum_c P[c][i] + w[i])
//   out[i] = sum_j relu(sigmoid(-zp_j) * tanh(hp_j)) * Wout_j + bout
// with zp = s*vz+cz, hp = s*vh+ch (1-sigmoid(x) == sigmoid(-x)).
// ---------------------------------------------------------------------------
__global__ void k_out(const float* __restrict__ partials, const float* __restrict__ dinv,
                      const float* __restrict__ w, const float* __restrict__ coeff,
                      const float* __restrict__ Wout, const float* __restrict__ bout,
                      float* __restrict__ out, int N, int nranges) {
    __shared__ float c[5 * HIDDEN];
    __shared__ float b0;
    if (threadIdx.x < 4 * HIDDEN) c[threadIdx.x] = coeff[threadIdx.x];
    if (threadIdx.x < HIDDEN) c[4 * HIDDEN + threadIdx.x] = Wout[threadIdx.x];
    if (threadIdx.x == 0) b0 = bout[0];
    __syncthreads();
    int i = blockIdx.x * blockDim.x + threadIdx.x;
    if (i < N) {
        int r = i / RANGE, local = i % RANGE;
        const float* p = partials + (size_t)r * RANGE + local;
        float g = w[i];
        #pragma unroll
        for (int k = 0; k < G_CHUNKS; ++k)
            g += p[(size_t)k * nranges * RANGE];
        float si = dinv[i] * g;
        float acc = b0;
        #pragma unroll
        for (int j = 0; j < HIDDEN; ++j) {
            float zp = fminf(fmaxf(si * c[j] + c[64 + j], -30.f), 30.f);
            float hp = fminf(fmaxf(si * c[128 + j] + c[192 + j], -15.f), 15.f);
            float a  = __expf(2.0f * hp);                 // tanh(hp)=(a-1)/(a+1)
            float t  = (a - 1.0f) / (a + 1.0f);
            float zn = 1.0f / (1.0f + __expf(zp));        // 1 - sigmoid(zp)
            float hn = zn * t;
            hn = hn > 0.0f ? hn : 0.0f;
            acc = fmaf(hn, c[256 + j], acc);
        }
        out[i] = acc;
    }
}

extern "C" void kernel_launch(void* const* d_in, const int* in_sizes, int n_in,
                              void* d_out, int out_size, void* d_ws, size_t ws_size,
                              hipStream_t stream) {
    const float* x    = (const float*)d_in[0];
    const float* ew   = (const float*)d_in[1];
    const float* Wz   = (const float*)d_in[2];
    const float* bz   = (const float*)d_in[3];
    const float* Lz   = (const float*)d_in[4];
    const float* lbz  = (const float*)d_in[5];
    // d_in[6..9] = Wr, br, Lr, lbr — dead (H0 = 0 makes the R gate unused)
    const float* Wh   = (const float*)d_in[10];
    const float* bh   = (const float*)d_in[11];
    const float* Lh   = (const float*)d_in[12];
    const float* lbh  = (const float*)d_in[13];
    const float* Wout = (const float*)d_in[14];
    const float* bout = (const float*)d_in[15];
    const int*   eidx = (const int*)d_in[16];

    const int N = in_sizes[0];          // x is [N,1]
    const int E = in_sizes[1];          // edge_weight is [E]
    const int* src = eidx;              // edge_index[0]
    const int* dst = eidx + E;          // edge_index[1]

    const int nranges = (N + RANGE - 1) / RANGE;   // 7 for N=100000

    float* partials = (float*)d_ws;                               // G*nranges*RANGE
    float* dinv     = partials + (size_t)G_CHUNKS * nranges * RANGE;  // N
    float* w        = dinv + N;                                   // N
    float* coeff    = w + N;                                      // 4*HIDDEN

    const int TB = 256;
    const int grid_bin = G_CHUNKS * nranges;   // 224 blocks, 64 KB LDS -> 2/CU

    // Pass A: bin edge weights -> deg partials
    k_bin<false><<<grid_bin, 1024, 0, stream>>>(dst, src, ew, (const float*)nullptr,
                                                partials, N, E, nranges);
    // deg -> dinv, w = dinv*x; plus GRU coefficient fusion
    k_node<<<(N + TB - 1) / TB, TB, 0, stream>>>(x, partials, dinv, w, N, nranges,
                                                 Wz, bz, Lz, lbz, Wh, bh, Lh, lbh, coeff);
    // Pass B: bin w[src]*ew -> aggregation partials
    k_bin<true><<<grid_bin, 1024, 0, stream>>>(dst, src, ew, w,
                                               partials, N, E, nranges);
    // Reduce + fused GRU + output head
    k_out<<<(N + TB - 1) / TB, TB, 0, stream>>>(partials, dinv, w, coeff, Wout, bout,
                                                (float*)d_out, N, nranges);
}